// Round 2
// baseline (635.390 us; speedup 1.0000x reference)
//
#include <hip/hip_runtime.h>
#include <math.h>

// Problem constants (B=4, C=64, H=W=L=16)
#define BATCH 4
#define CH    64
#define NVOX  4096      // 16*16*16
#define NGRP  32
#define CPG   2         // channels per group
#define EPS   1e-5f

// ---------------------------------------------------------------------------
// Kernel 1: GroupNorm statistics. One block per (b, g): 8192 elements.
// ---------------------------------------------------------------------------
__global__ __launch_bounds__(256) void k_gnstats(const float* __restrict__ x,
                                                 float* __restrict__ stats) {
    int bg = blockIdx.x;                       // 0..127  == b*32 + g
    const float4* p4 = (const float4*)(x + (size_t)bg * (CPG * NVOX));
    float s = 0.f, sq = 0.f;
    for (int i = threadIdx.x; i < (CPG * NVOX) / 4; i += 256) {
        float4 v = p4[i];
        s  += v.x + v.y + v.z + v.w;
        sq += v.x * v.x + v.y * v.y + v.z * v.z + v.w * v.w;
    }
    for (int off = 32; off; off >>= 1) {
        s  += __shfl_down(s, off);
        sq += __shfl_down(sq, off);
    }
    __shared__ float ls[4], lq[4];
    int wid = threadIdx.x >> 6;
    if ((threadIdx.x & 63) == 0) { ls[wid] = s; lq[wid] = sq; }
    __syncthreads();
    if (threadIdx.x == 0) {
        s  = ls[0] + ls[1] + ls[2] + ls[3];
        sq = lq[0] + lq[1] + lq[2] + lq[3];
        float mean = s / (float)(CPG * NVOX);
        float var  = sq / (float)(CPG * NVOX) - mean * mean;
        stats[bg]       = mean;
        stats[128 + bg] = rsqrtf(var + EPS);
    }
}

// ---------------------------------------------------------------------------
// Kernel 2: fused normalize + QKV projection (192x64 per voxel).
// Grid: 4 batches * 64 n-tiles of 64 voxels. qkv layout: [B][192][N].
// ---------------------------------------------------------------------------
__global__ __launch_bounds__(256) void k_qkv(const float* __restrict__ x,
                                             const float* __restrict__ stats,
                                             const float* __restrict__ gw,
                                             const float* __restrict__ gb,
                                             const float* __restrict__ Wqkv,
                                             float* __restrict__ qkv) {
    int b  = blockIdx.x >> 6;
    int n0 = (blockIdx.x & 63) * 64;
    __shared__ float nm[64][64];
    int t = threadIdx.x;
    // load + normalize tile [64c][64n], float4 over n
    for (int i = t; i < 64 * 16; i += 256) {
        int c = i >> 4;
        int n = (i & 15) * 4;
        float4 v = *(const float4*)&x[((size_t)(b * CH + c)) * NVOX + n0 + n];
        int g = c >> 1;
        float mean = stats[b * NGRP + g];
        float rstd = stats[128 + b * NGRP + g];
        float sc = rstd * gw[c];
        float sh = gb[c] - mean * sc;
        nm[c][n + 0] = v.x * sc + sh;
        nm[c][n + 1] = v.y * sc + sh;
        nm[c][n + 2] = v.z * sc + sh;
        nm[c][n + 3] = v.w * sc + sh;
    }
    __syncthreads();
    int nl = t & 63;
    int dg = t >> 6;                      // 0..3 -> 48 rows each
    float r[64];
    #pragma unroll
    for (int c = 0; c < 64; ++c) r[c] = nm[c][nl];
    for (int j = 0; j < 48; ++j) {
        int d = dg * 48 + j;
        const float* w = &Wqkv[d * 64];
        float acc = 0.f;
        #pragma unroll
        for (int c = 0; c < 64; ++c) acc += w[c] * r[c];
        qkv[((size_t)(b * 192 + d)) * NVOX + n0 + nl] = acc;
    }
}

// ---------------------------------------------------------------------------
// Kernel 3: flash attention, fp32. One block per (b, q-tile of 64).
// K/V tiles of 32 columns; online softmax (running m,l per q row).
// ---------------------------------------------------------------------------
__global__ __launch_bounds__(256) void k_attn(const float* __restrict__ qkv,
                                              float* __restrict__ Obuf) {
    int b   = blockIdx.x >> 6;
    int q0g = (blockIdx.x & 63) * 64;
    const float* Q = qkv + ((size_t)b * 192 + 0)   * NVOX;
    const float* K = qkv + ((size_t)b * 192 + 64)  * NVOX;
    const float* V = qkv + ((size_t)b * 192 + 128) * NVOX;

    __shared__ float Qs[64][64];
    __shared__ float Ks[64][32];
    __shared__ float Vs[64][33];   // +1 pad: PV reads Vs[c0..c0+3][k] conflict-free
    __shared__ float Ps[64][33];   // +1 pad: row ops and column reads conflict-free
    __shared__ float mS[64], lS[64], aS[64];

    int t = threadIdx.x;
    // Q tile, pre-scaled by 1/sqrt(C)=1/8
    for (int i = t; i < 64 * 16; i += 256) {
        int c = i >> 4;
        int q = (i & 15) * 4;
        float4 v = *(const float4*)&Q[(size_t)c * NVOX + q0g + q];
        Qs[c][q + 0] = v.x * 0.125f;
        Qs[c][q + 1] = v.y * 0.125f;
        Qs[c][q + 2] = v.z * 0.125f;
        Qs[c][q + 3] = v.w * 0.125f;
    }
    if (t < 64) { mS[t] = -1e30f; lS[t] = 0.f; }

    float acc[4][4];                       // [c][q]
    #pragma unroll
    for (int i = 0; i < 4; ++i)
        #pragma unroll
        for (int j = 0; j < 4; ++j) acc[i][j] = 0.f;

    const int qloc = (t & 15) * 4;         // 4 q rows (S and PV)
    const int kloc = (t >> 4) * 2;         // 2 k cols (S)
    const int c0   = (t >> 4) * 4;         // 4 c rows (PV)
    __syncthreads();

    for (int kt = 0; kt < NVOX / 32; ++kt) {
        int k0g = kt * 32;
        // load K,V tiles: 2048 elems each, 8 per thread
        {
            int c = t >> 2;
            int k = (t & 3) * 8;
            float4 a  = *(const float4*)&K[(size_t)c * NVOX + k0g + k];
            float4 a2 = *(const float4*)&K[(size_t)c * NVOX + k0g + k + 4];
            Ks[c][k + 0] = a.x;  Ks[c][k + 1] = a.y;
            Ks[c][k + 2] = a.z;  Ks[c][k + 3] = a.w;
            Ks[c][k + 4] = a2.x; Ks[c][k + 5] = a2.y;
            Ks[c][k + 6] = a2.z; Ks[c][k + 7] = a2.w;
            float4 v  = *(const float4*)&V[(size_t)c * NVOX + k0g + k];
            float4 v2 = *(const float4*)&V[(size_t)c * NVOX + k0g + k + 4];
            Vs[c][k + 0] = v.x;  Vs[c][k + 1] = v.y;
            Vs[c][k + 2] = v.z;  Vs[c][k + 3] = v.w;
            Vs[c][k + 4] = v2.x; Vs[c][k + 5] = v2.y;
            Vs[c][k + 6] = v2.z; Vs[c][k + 7] = v2.w;
        }
        __syncthreads();

        // S tile: 4q x 2k per thread, dot over 64 c
        float s00 = 0.f, s01 = 0.f, s10 = 0.f, s11 = 0.f;
        float s20 = 0.f, s21 = 0.f, s30 = 0.f, s31 = 0.f;
        #pragma unroll
        for (int c = 0; c < 64; ++c) {
            float q0 = Qs[c][qloc + 0];
            float q1 = Qs[c][qloc + 1];
            float q2 = Qs[c][qloc + 2];
            float q3 = Qs[c][qloc + 3];
            float k0 = Ks[c][kloc + 0];
            float k1 = Ks[c][kloc + 1];
            s00 += q0 * k0; s01 += q0 * k1;
            s10 += q1 * k0; s11 += q1 * k1;
            s20 += q2 * k0; s21 += q2 * k1;
            s30 += q3 * k0; s31 += q3 * k1;
        }
        Ps[qloc + 0][kloc + 0] = s00; Ps[qloc + 0][kloc + 1] = s01;
        Ps[qloc + 1][kloc + 0] = s10; Ps[qloc + 1][kloc + 1] = s11;
        Ps[qloc + 2][kloc + 0] = s20; Ps[qloc + 2][kloc + 1] = s21;
        Ps[qloc + 3][kloc + 0] = s30; Ps[qloc + 3][kloc + 1] = s31;
        __syncthreads();

        // online softmax on rows; wave 0 (one lane per q row)
        if (t < 64) {
            float m_old = mS[t];
            float mx = m_old;
            #pragma unroll
            for (int k = 0; k < 32; ++k) mx = fmaxf(mx, Ps[t][k]);
            float al = __expf(m_old - mx);
            float sum = 0.f;
            #pragma unroll
            for (int k = 0; k < 32; ++k) {
                float p = __expf(Ps[t][k] - mx);
                Ps[t][k] = p;
                sum += p;
            }
            lS[t] = lS[t] * al + sum;
            mS[t] = mx;
            aS[t] = al;
        }
        __syncthreads();

        // rescale + PV accumulate: 4c x 4q per thread
        float a0 = aS[qloc + 0], a1 = aS[qloc + 1];
        float a2 = aS[qloc + 2], a3 = aS[qloc + 3];
        #pragma unroll
        for (int i = 0; i < 4; ++i) {
            acc[i][0] *= a0; acc[i][1] *= a1;
            acc[i][2] *= a2; acc[i][3] *= a3;
        }
        #pragma unroll
        for (int k = 0; k < 32; ++k) {
            float p0 = Ps[qloc + 0][k], p1 = Ps[qloc + 1][k];
            float p2 = Ps[qloc + 2][k], p3 = Ps[qloc + 3][k];
            float v0 = Vs[c0 + 0][k], v1 = Vs[c0 + 1][k];
            float v2 = Vs[c0 + 2][k], v3 = Vs[c0 + 3][k];
            acc[0][0] += v0 * p0; acc[0][1] += v0 * p1;
            acc[0][2] += v0 * p2; acc[0][3] += v0 * p3;
            acc[1][0] += v1 * p0; acc[1][1] += v1 * p1;
            acc[1][2] += v1 * p2; acc[1][3] += v1 * p3;
            acc[2][0] += v2 * p0; acc[2][1] += v2 * p1;
            acc[2][2] += v2 * p2; acc[2][3] += v2 * p3;
            acc[3][0] += v3 * p0; acc[3][1] += v3 * p1;
            acc[3][2] += v3 * p2; acc[3][3] += v3 * p3;
        }
        __syncthreads();
    }

    // epilogue: divide by l, store [c][q] tile
    float il0 = 1.f / lS[qloc + 0];
    float il1 = 1.f / lS[qloc + 1];
    float il2 = 1.f / lS[qloc + 2];
    float il3 = 1.f / lS[qloc + 3];
    #pragma unroll
    for (int i = 0; i < 4; ++i) {
        float4 o;
        o.x = acc[i][0] * il0;
        o.y = acc[i][1] * il1;
        o.z = acc[i][2] * il2;
        o.w = acc[i][3] * il3;
        *(float4*)&Obuf[((size_t)(b * CH + c0 + i)) * NVOX + q0g + qloc] = o;
    }
}

// ---------------------------------------------------------------------------
// Kernel 4: output projection (64x64) + bias + residual.
// ---------------------------------------------------------------------------
__global__ __launch_bounds__(256) void k_outproj(const float* __restrict__ Obuf,
                                                 const float* __restrict__ Wout,
                                                 const float* __restrict__ obias,
                                                 const float* __restrict__ x,
                                                 float* __restrict__ out) {
    int b  = blockIdx.x >> 6;
    int n0 = (blockIdx.x & 63) * 64;
    __shared__ float os[64][64];
    int t = threadIdx.x;
    for (int i = t; i < 64 * 16; i += 256) {
        int c = i >> 4;
        int n = (i & 15) * 4;
        float4 v = *(const float4*)&Obuf[((size_t)(b * CH + c)) * NVOX + n0 + n];
        os[c][n + 0] = v.x; os[c][n + 1] = v.y;
        os[c][n + 2] = v.z; os[c][n + 3] = v.w;
    }
    __syncthreads();
    int nl = t & 63;
    int dg = t >> 6;                       // 0..3 -> 16 rows each
    float r[64];
    #pragma unroll
    for (int c = 0; c < 64; ++c) r[c] = os[c][nl];
    for (int j = 0; j < 16; ++j) {
        int d = dg * 16 + j;
        const float* w = &Wout[d * 64];
        float acc = obias[d];
        #pragma unroll
        for (int c = 0; c < 64; ++c) acc += w[c] * r[c];
        size_t idx = ((size_t)(b * CH + d)) * NVOX + n0 + nl;
        out[idx] = acc + x[idx];
    }
}

// ---------------------------------------------------------------------------
extern "C" void kernel_launch(void* const* d_in, const int* in_sizes, int n_in,
                              void* d_out, int out_size, void* d_ws, size_t ws_size,
                              hipStream_t stream) {
    const float* x     = (const float*)d_in[0];
    const float* gw    = (const float*)d_in[1];
    const float* gb    = (const float*)d_in[2];
    const float* Wqkv  = (const float*)d_in[3];
    const float* Wout  = (const float*)d_in[4];
    const float* obias = (const float*)d_in[5];
    float* out = (float*)d_out;

    float* ws    = (float*)d_ws;
    float* stats = ws;                                   // 256 floats
    float* qkv   = ws + 256;                             // B*192*N
    float* Obuf  = qkv + (size_t)BATCH * 192 * NVOX;     // B*64*N

    k_gnstats<<<BATCH * NGRP, 256, 0, stream>>>(x, stats);
    k_qkv   <<<BATCH * 64,   256, 0, stream>>>(x, stats, gw, gb, Wqkv, qkv);
    k_attn  <<<BATCH * 64,   256, 0, stream>>>(qkv, Obuf);
    k_outproj<<<BATCH * 64,  256, 0, stream>>>(Obuf, Wout, obias, x, out);
}

// Round 4
// 196.234 us; speedup vs baseline: 3.2379x; 3.2379x over previous
//
#include <hip/hip_runtime.h>
#include <hip/hip_bf16.h>
#include <math.h>

// Problem constants (B=4, C=64, H=W=L=16)
#define BATCH 4
#define CH    64
#define NVOX  4096
#define NGRP  32
#define EPS   1e-5f

typedef float f32x4 __attribute__((ext_vector_type(4)));
typedef short s16x8 __attribute__((ext_vector_type(8)));

static __device__ inline unsigned short f2bf(float f) {
    union { __hip_bfloat16 h; unsigned short u; } cv;
    cv.h = __float2bfloat16(f);
    return cv.u;
}

// ---------------------------------------------------------------------------
// Kernel 1: GroupNorm statistics. One block per (b, g): 8192 elements.
// ---------------------------------------------------------------------------
__global__ __launch_bounds__(256) void k_gnstats(const float* __restrict__ x,
                                                 float* __restrict__ stats) {
    int bg = blockIdx.x;                       // b*32 + g
    const float4* p4 = (const float4*)(x + (size_t)bg * (2 * NVOX));
    float s = 0.f, sq = 0.f;
    for (int i = threadIdx.x; i < (2 * NVOX) / 4; i += 256) {
        float4 v = p4[i];
        s  += v.x + v.y + v.z + v.w;
        sq += v.x * v.x + v.y * v.y + v.z * v.z + v.w * v.w;
    }
    for (int off = 32; off; off >>= 1) {
        s  += __shfl_down(s, off);
        sq += __shfl_down(sq, off);
    }
    __shared__ float ls[4], lq[4];
    int wid = threadIdx.x >> 6;
    if ((threadIdx.x & 63) == 0) { ls[wid] = s; lq[wid] = sq; }
    __syncthreads();
    if (threadIdx.x == 0) {
        s  = ls[0] + ls[1] + ls[2] + ls[3];
        sq = lq[0] + lq[1] + lq[2] + lq[3];
        float mean = s / (float)(2 * NVOX);
        float var  = sq / (float)(2 * NVOX) - mean * mean;
        stats[bg]       = mean;
        stats[128 + bg] = rsqrtf(var + EPS);
    }
}

// ---------------------------------------------------------------------------
// Kernel 2: fused normalize + QKV projection. Outputs bf16:
//   Qb [B][N][64]  (pre-scaled by 1/sqrt(C)=0.125)
//   Kb [B][N][64]
//   Vb [B][64][N]
// ---------------------------------------------------------------------------
__global__ __launch_bounds__(256) void k_qkv(const float* __restrict__ x,
                                             const float* __restrict__ stats,
                                             const float* __restrict__ gw,
                                             const float* __restrict__ gb,
                                             const float* __restrict__ W,
                                             unsigned short* __restrict__ Qb,
                                             unsigned short* __restrict__ Kb,
                                             unsigned short* __restrict__ Vb) {
    int b  = blockIdx.x >> 6;
    int n0 = (blockIdx.x & 63) * 64;
    int t  = threadIdx.x;
    __shared__ float nm[64][64];                 // [c][n]
    __shared__ alignas(16) unsigned short tb[64][72];  // [n][d] transpose buf

    for (int i = t; i < 64 * 16; i += 256) {
        int c = i >> 4;
        int n = (i & 15) * 4;
        float4 v = *(const float4*)&x[((size_t)(b * CH + c)) * NVOX + n0 + n];
        float mean = stats[b * NGRP + (c >> 1)];
        float rstd = stats[128 + b * NGRP + (c >> 1)];
        float sc = rstd * gw[c];
        float sh = gb[c] - mean * sc;
        nm[c][n + 0] = v.x * sc + sh;
        nm[c][n + 1] = v.y * sc + sh;
        nm[c][n + 2] = v.z * sc + sh;
        nm[c][n + 3] = v.w * sc + sh;
    }
    __syncthreads();

    int nl = t & 63;
    int dg = t >> 6;
    float r[64];
    #pragma unroll
    for (int c = 0; c < 64; ++c) r[c] = nm[c][nl];

    // ---- Q round (rows 0..63 of W), scaled by 0.125 ----
    for (int j = 0; j < 16; ++j) {
        int d = dg * 16 + j;
        const float* w = &W[d * 64];
        float acc = 0.f;
        #pragma unroll
        for (int c = 0; c < 64; ++c) acc += w[c] * r[c];
        tb[nl][d] = f2bf(acc * 0.125f);
    }
    __syncthreads();
    {
        int n = t >> 2, d0 = (t & 3) * 16;
        s16x8 a0 = *(const s16x8*)&tb[n][d0];
        s16x8 a1 = *(const s16x8*)&tb[n][d0 + 8];
        size_t base = ((size_t)(b * NVOX + n0 + n)) * 64 + d0;
        *(s16x8*)&Qb[base]     = a0;
        *(s16x8*)&Qb[base + 8] = a1;
    }
    __syncthreads();

    // ---- K round (rows 64..127) ----
    for (int j = 0; j < 16; ++j) {
        int d = dg * 16 + j;
        const float* w = &W[(64 + d) * 64];
        float acc = 0.f;
        #pragma unroll
        for (int c = 0; c < 64; ++c) acc += w[c] * r[c];
        tb[nl][d] = f2bf(acc);
    }
    __syncthreads();
    {
        int n = t >> 2, d0 = (t & 3) * 16;
        s16x8 a0 = *(const s16x8*)&tb[n][d0];
        s16x8 a1 = *(const s16x8*)&tb[n][d0 + 8];
        size_t base = ((size_t)(b * NVOX + n0 + n)) * 64 + d0;
        *(s16x8*)&Kb[base]     = a0;
        *(s16x8*)&Kb[base + 8] = a1;
    }

    // ---- V round (rows 128..191), c-major output ----
    for (int j = 0; j < 16; ++j) {
        int d = dg * 16 + j;
        const float* w = &W[(128 + d) * 64];
        float acc = 0.f;
        #pragma unroll
        for (int c = 0; c < 64; ++c) acc += w[c] * r[c];
        Vb[((size_t)(b * 64 + d)) * NVOX + n0 + nl] = f2bf(acc);
    }
}

// ---------------------------------------------------------------------------
// Kernel 3: flash attention, bf16 MFMA (16x16x32). One block per (b, 64-q
// tile); 4 waves, each owning one 16-q row block. KV tiles of 64.
//   S-tile:  A = Q frag (row q = lane&15, k-slice c), B = K^T frag.
//   D layout (m89): col = lane&15, row = (lane>>4)*4 + reg.
//   Online softmax wave-parallel via shfl_xor within 16-lane groups.
//   PV: P staged per-wave in padded LDS; A = P frag, B = V^T frag.
// Output Obuf n-major [B][N][64] fp32.
// ---------------------------------------------------------------------------
__global__ __launch_bounds__(256) void k_attn(const unsigned short* __restrict__ Qb,
                                              const unsigned short* __restrict__ Kb,
                                              const unsigned short* __restrict__ Vb,
                                              float* __restrict__ Obuf) {
    int b    = blockIdx.x >> 6;
    int q0   = (blockIdx.x & 63) * 64;
    int t    = threadIdx.x;
    int lane = t & 63;
    int w    = t >> 6;

    __shared__ alignas(16) unsigned short Ks[64][72];     // [k][c] +8 pad
    __shared__ alignas(16) unsigned short Vs[64][72];     // [c][k] +8 pad
    __shared__ alignas(16) unsigned short Ps[4][16][72];  // per-wave [q][k]

    const unsigned short* Qp = Qb + (size_t)b * NVOX * 64;
    const unsigned short* Kp = Kb + (size_t)b * NVOX * 64;
    const unsigned short* Vp = Vb + (size_t)b * 64 * NVOX;

    // Q fragments (held for whole kernel): row q = lane&15, c-slices of 8
    int l15 = lane & 15;
    int g4  = lane >> 4;            // 0..3
    int csl = g4 * 8;
    int qrow = q0 + w * 16 + l15;
    s16x8 qf0 = *(const s16x8*)&Qp[(size_t)qrow * 64 + csl];
    s16x8 qf1 = *(const s16x8*)&Qp[(size_t)qrow * 64 + csl + 32];

    f32x4 acc_o[4] = {};            // [c-tile][reg], rows q = g4*4+reg
    float m_r[4], l_r[4];
    #pragma unroll
    for (int i = 0; i < 4; ++i) { m_r[i] = -1e30f; l_r[i] = 0.f; }

    // staging: thread t covers row sr, 32B chunk sc
    int sr = t >> 2;                // 0..63
    int sc = (t & 3) * 16;          // bf16 col offset

    s16x8 kr0, kr1, vr0, vr1;
    {   // prologue loads (kv block 0)
        const s16x8* pk = (const s16x8*)&Kp[(size_t)sr * 64 + sc];
        kr0 = pk[0]; kr1 = pk[1];
        const s16x8* pv = (const s16x8*)&Vp[(size_t)sr * NVOX + sc];
        vr0 = pv[0]; vr1 = pv[1];
    }

    for (int it = 0; it < NVOX / 64; ++it) {
        // write staged tile to LDS
        *(s16x8*)&Ks[sr][sc]     = kr0;
        *(s16x8*)&Ks[sr][sc + 8] = kr1;
        *(s16x8*)&Vs[sr][sc]     = vr0;
        *(s16x8*)&Vs[sr][sc + 8] = vr1;
        __syncthreads();

        // issue next tile's global loads (latency hides under compute)
        if (it < NVOX / 64 - 1) {
            int k0n = (it + 1) * 64;
            const s16x8* pk = (const s16x8*)&Kp[((size_t)(k0n + sr)) * 64 + sc];
            kr0 = pk[0]; kr1 = pk[1];
            const s16x8* pv = (const s16x8*)&Vp[(size_t)sr * NVOX + k0n + sc];
            vr0 = pv[0]; vr1 = pv[1];
        }

        // ---- S = Q K^T  (4 k-tiles of 16) ----
        f32x4 sacc[4];
        #pragma unroll
        for (int kt = 0; kt < 4; ++kt) {
            s16x8 kf0 = *(const s16x8*)&Ks[kt * 16 + l15][csl];
            s16x8 kf1 = *(const s16x8*)&Ks[kt * 16 + l15][csl + 32];
            f32x4 z = {0.f, 0.f, 0.f, 0.f};
            sacc[kt] = __builtin_amdgcn_mfma_f32_16x16x32_bf16(qf0, kf0, z, 0, 0, 0);
            sacc[kt] = __builtin_amdgcn_mfma_f32_16x16x32_bf16(qf1, kf1, sacc[kt], 0, 0, 0);
        }

        // ---- online softmax (rows q = g4*4 + reg) ----
        float al[4];
        #pragma unroll
        for (int reg = 0; reg < 4; ++reg) {
            float rmax = fmaxf(fmaxf(sacc[0][reg], sacc[1][reg]),
                               fmaxf(sacc[2][reg], sacc[3][reg]));
            rmax = fmaxf(rmax, __shfl_xor(rmax, 1));
            rmax = fmaxf(rmax, __shfl_xor(rmax, 2));
            rmax = fmaxf(rmax, __shfl_xor(rmax, 4));
            rmax = fmaxf(rmax, __shfl_xor(rmax, 8));
            float mn = fmaxf(m_r[reg], rmax);
            al[reg] = __expf(m_r[reg] - mn);
            m_r[reg] = mn;
        }
        float p[4][4];   // [kt][reg]
        #pragma unroll
        for (int kt = 0; kt < 4; ++kt)
            #pragma unroll
            for (int reg = 0; reg < 4; ++reg)
                p[kt][reg] = __expf(sacc[kt][reg] - m_r[reg]);
        #pragma unroll
        for (int reg = 0; reg < 4; ++reg) {
            float rs = p[0][reg] + p[1][reg] + p[2][reg] + p[3][reg];
            rs += __shfl_xor(rs, 1);
            rs += __shfl_xor(rs, 2);
            rs += __shfl_xor(rs, 4);
            rs += __shfl_xor(rs, 8);
            l_r[reg] = l_r[reg] * al[reg] + rs;
        }
        // write P (bf16) to per-wave LDS: row g4*4+reg, col kt*16+l15
        #pragma unroll
        for (int kt = 0; kt < 4; ++kt)
            #pragma unroll
            for (int reg = 0; reg < 4; ++reg)
                Ps[w][g4 * 4 + reg][kt * 16 + l15] = f2bf(p[kt][reg]);
        // rescale O accumulator
        #pragma unroll
        for (int ct = 0; ct < 4; ++ct)
            #pragma unroll
            for (int reg = 0; reg < 4; ++reg)
                acc_o[ct][reg] *= al[reg];

        // ---- PV: A = P frag (row q = l15, k-slice), B = V^T frag ----
        s16x8 pf0 = *(const s16x8*)&Ps[w][l15][csl];
        s16x8 pf1 = *(const s16x8*)&Ps[w][l15][csl + 32];
        #pragma unroll
        for (int ct = 0; ct < 4; ++ct) {
            s16x8 vf0 = *(const s16x8*)&Vs[ct * 16 + l15][csl];
            s16x8 vf1 = *(const s16x8*)&Vs[ct * 16 + l15][csl + 32];
            acc_o[ct] = __builtin_amdgcn_mfma_f32_16x16x32_bf16(pf0, vf0, acc_o[ct], 0, 0, 0);
            acc_o[ct] = __builtin_amdgcn_mfma_f32_16x16x32_bf16(pf1, vf1, acc_o[ct], 0, 0, 0);
        }
        __syncthreads();   // all LDS reads done before next overwrite
    }

    // epilogue: normalize rows, store n-major [B][N][64]
    float inv[4];
    #pragma unroll
    for (int reg = 0; reg < 4; ++reg) inv[reg] = 1.f / l_r[reg];
    #pragma unroll
    for (int ct = 0; ct < 4; ++ct)
        #pragma unroll
        for (int reg = 0; reg < 4; ++reg) {
            int q = q0 + w * 16 + g4 * 4 + reg;
            Obuf[((size_t)(b * NVOX + q)) * 64 + ct * 16 + l15] =
                acc_o[ct][reg] * inv[reg];
        }
}

// ---------------------------------------------------------------------------
// Kernel 4: output projection (64x64) + bias + residual. Obuf is n-major.
// ---------------------------------------------------------------------------
__global__ __launch_bounds__(256) void k_outproj(const float* __restrict__ Obuf,
                                                 const float* __restrict__ Wout,
                                                 const float* __restrict__ obias,
                                                 const float* __restrict__ x,
                                                 float* __restrict__ out) {
    int b  = blockIdx.x >> 6;
    int n0 = (blockIdx.x & 63) * 64;
    int t  = threadIdx.x;
    __shared__ float os[64][65];       // [n][c] +1 pad (row reads by lane)
    for (int i = t; i < 64 * 16; i += 256) {
        int n  = i >> 4;
        int c4 = (i & 15) * 4;
        float4 v = *(const float4*)&Obuf[((size_t)(b * NVOX + n0 + n)) * 64 + c4];
        os[n][c4 + 0] = v.x; os[n][c4 + 1] = v.y;
        os[n][c4 + 2] = v.z; os[n][c4 + 3] = v.w;
    }
    __syncthreads();
    int nl = t & 63;
    int dg = t >> 6;
    float r[64];
    #pragma unroll
    for (int c = 0; c < 64; ++c) r[c] = os[nl][c];
    for (int j = 0; j < 16; ++j) {
        int d = dg * 16 + j;
        const float* wv = &Wout[d * 64];
        float acc = obias[d];
        #pragma unroll
        for (int c = 0; c < 64; ++c) acc += wv[c] * r[c];
        size_t idx = ((size_t)(b * CH + d)) * NVOX + n0 + nl;
        out[idx] = acc + x[idx];
    }
}

// ---------------------------------------------------------------------------
extern "C" void kernel_launch(void* const* d_in, const int* in_sizes, int n_in,
                              void* d_out, int out_size, void* d_ws, size_t ws_size,
                              hipStream_t stream) {
    const float* x     = (const float*)d_in[0];
    const float* gw    = (const float*)d_in[1];
    const float* gb    = (const float*)d_in[2];
    const float* Wqkv  = (const float*)d_in[3];
    const float* Wout  = (const float*)d_in[4];
    const float* obias = (const float*)d_in[5];
    float* out = (float*)d_out;

    float* ws    = (float*)d_ws;
    float* stats = ws;                                     // 256 floats
    unsigned short* Qb = (unsigned short*)(ws + 256);      // 1M bf16
    unsigned short* Kb = Qb + (size_t)BATCH * NVOX * 64;
    unsigned short* Vb = Kb + (size_t)BATCH * NVOX * 64;
    float* Obuf = (float*)(Vb + (size_t)BATCH * NVOX * 64);// B*N*64 f32

    k_gnstats<<<BATCH * NGRP, 256, 0, stream>>>(x, stats);
    k_qkv   <<<BATCH * 64,   256, 0, stream>>>(x, stats, gw, gb, Wqkv, Qb, Kb, Vb);
    k_attn  <<<BATCH * 64,   256, 0, stream>>>(Qb, Kb, Vb, Obuf);
    k_outproj<<<BATCH * 64,  256, 0, stream>>>(Obuf, Wout, obias, x, out);
}

// Round 6
// 190.677 us; speedup vs baseline: 3.3323x; 1.0291x over previous
//
#include <hip/hip_runtime.h>
#include <hip/hip_bf16.h>
#include <math.h>

// Problem constants (B=4, C=64, H=W=L=16)
#define BATCH 4
#define CH    64
#define NVOX  4096
#define NGRP  32
#define EPS   1e-5f
#define SPLITS 4
#define KVS   (NVOX / SPLITS)   // 1024 KV per split

typedef float f32x4 __attribute__((ext_vector_type(4)));
typedef short s16x8 __attribute__((ext_vector_type(8)));

static __device__ inline unsigned short f2bf(float f) {
    union { __hip_bfloat16 h; unsigned short u; } cv;
    cv.h = __float2bfloat16(f);
    return cv.u;
}

// ---------------------------------------------------------------------------
// Kernel 1: GroupNorm statistics. One block per (b, g): 8192 elements.
// ---------------------------------------------------------------------------
__global__ __launch_bounds__(256) void k_gnstats(const float* __restrict__ x,
                                                 float* __restrict__ stats) {
    int bg = blockIdx.x;                       // b*32 + g
    const float4* p4 = (const float4*)(x + (size_t)bg * (2 * NVOX));
    float s = 0.f, sq = 0.f;
    for (int i = threadIdx.x; i < (2 * NVOX) / 4; i += 256) {
        float4 v = p4[i];
        s  += v.x + v.y + v.z + v.w;
        sq += v.x * v.x + v.y * v.y + v.z * v.z + v.w * v.w;
    }
    for (int off = 32; off; off >>= 1) {
        s  += __shfl_down(s, off);
        sq += __shfl_down(sq, off);
    }
    __shared__ float ls[4], lq[4];
    int wid = threadIdx.x >> 6;
    if ((threadIdx.x & 63) == 0) { ls[wid] = s; lq[wid] = sq; }
    __syncthreads();
    if (threadIdx.x == 0) {
        s  = ls[0] + ls[1] + ls[2] + ls[3];
        sq = lq[0] + lq[1] + lq[2] + lq[3];
        float mean = s / (float)(2 * NVOX);
        float var  = sq / (float)(2 * NVOX) - mean * mean;
        stats[bg]       = mean;
        stats[128 + bg] = rsqrtf(var + EPS);
    }
}

// ---------------------------------------------------------------------------
// Kernel 2: fused normalize + QKV projection. Outputs bf16:
//   Qb [B][N][64]  (pre-scaled by 1/sqrt(C)=0.125)
//   Kb [B][N][64]
//   Vb [B][64][N]
// ---------------------------------------------------------------------------
__global__ __launch_bounds__(256) void k_qkv(const float* __restrict__ x,
                                             const float* __restrict__ stats,
                                             const float* __restrict__ gw,
                                             const float* __restrict__ gb,
                                             const float* __restrict__ W,
                                             unsigned short* __restrict__ Qb,
                                             unsigned short* __restrict__ Kb,
                                             unsigned short* __restrict__ Vb) {
    int b  = blockIdx.x >> 6;
    int n0 = (blockIdx.x & 63) * 64;
    int t  = threadIdx.x;
    __shared__ float nm[64][64];                 // [c][n]
    __shared__ alignas(16) unsigned short tb[64][72];  // [n][d] transpose buf

    for (int i = t; i < 64 * 16; i += 256) {
        int c = i >> 4;
        int n = (i & 15) * 4;
        float4 v = *(const float4*)&x[((size_t)(b * CH + c)) * NVOX + n0 + n];
        float mean = stats[b * NGRP + (c >> 1)];
        float rstd = stats[128 + b * NGRP + (c >> 1)];
        float sc = rstd * gw[c];
        float sh = gb[c] - mean * sc;
        nm[c][n + 0] = v.x * sc + sh;
        nm[c][n + 1] = v.y * sc + sh;
        nm[c][n + 2] = v.z * sc + sh;
        nm[c][n + 3] = v.w * sc + sh;
    }
    __syncthreads();

    int nl = t & 63;
    int dg = t >> 6;
    float r[64];
    #pragma unroll
    for (int c = 0; c < 64; ++c) r[c] = nm[c][nl];

    // ---- Q round (rows 0..63 of W), scaled by 0.125 ----
    #pragma unroll 4
    for (int j = 0; j < 16; ++j) {
        int d = dg * 16 + j;
        const float* w = &W[d * 64];
        float acc = 0.f;
        #pragma unroll
        for (int c = 0; c < 64; ++c) acc += w[c] * r[c];
        tb[nl][d] = f2bf(acc * 0.125f);
    }
    __syncthreads();
    {
        int n = t >> 2, d0 = (t & 3) * 16;
        s16x8 a0 = *(const s16x8*)&tb[n][d0];
        s16x8 a1 = *(const s16x8*)&tb[n][d0 + 8];
        size_t base = ((size_t)(b * NVOX + n0 + n)) * 64 + d0;
        *(s16x8*)&Qb[base]     = a0;
        *(s16x8*)&Qb[base + 8] = a1;
    }
    __syncthreads();

    // ---- K round (rows 64..127) ----
    #pragma unroll 4
    for (int j = 0; j < 16; ++j) {
        int d = dg * 16 + j;
        const float* w = &W[(64 + d) * 64];
        float acc = 0.f;
        #pragma unroll
        for (int c = 0; c < 64; ++c) acc += w[c] * r[c];
        tb[nl][d] = f2bf(acc);
    }
    __syncthreads();
    {
        int n = t >> 2, d0 = (t & 3) * 16;
        s16x8 a0 = *(const s16x8*)&tb[n][d0];
        s16x8 a1 = *(const s16x8*)&tb[n][d0 + 8];
        size_t base = ((size_t)(b * NVOX + n0 + n)) * 64 + d0;
        *(s16x8*)&Kb[base]     = a0;
        *(s16x8*)&Kb[base + 8] = a1;
    }

    // ---- V round (rows 128..191), c-major output ----
    #pragma unroll 4
    for (int j = 0; j < 16; ++j) {
        int d = dg * 16 + j;
        const float* w = &W[(128 + d) * 64];
        float acc = 0.f;
        #pragma unroll
        for (int c = 0; c < 64; ++c) acc += w[c] * r[c];
        Vb[((size_t)(b * 64 + d)) * NVOX + n0 + nl] = f2bf(acc);
    }
}

// ---------------------------------------------------------------------------
// Kernel 3: flash attention, bf16 MFMA (16x16x32), KV-split-4.
// Grid: (b, qtile64, split) = 1024 blocks (4/CU). Each block handles a
// 1024-wide KV range, writes UNNORMALIZED partial O + per-row (m, l).
// ---------------------------------------------------------------------------
__global__ __launch_bounds__(256) void k_attn(const unsigned short* __restrict__ Qb,
                                              const unsigned short* __restrict__ Kb,
                                              const unsigned short* __restrict__ Vb,
                                              float* __restrict__ Opart,
                                              float* __restrict__ Mpart,
                                              float* __restrict__ Lpart) {
    int split = blockIdx.x & 3;
    int bq    = blockIdx.x >> 2;
    int b     = bq >> 6;
    int q0    = (bq & 63) * 64;
    int t     = threadIdx.x;
    int lane  = t & 63;
    int w     = t >> 6;
    const int kbase = split * KVS;

    __shared__ alignas(16) unsigned short Ks[64][72];     // [k][c] +8 pad
    __shared__ alignas(16) unsigned short Vs[64][72];     // [c][k] +8 pad
    __shared__ alignas(16) unsigned short Ps[4][16][72];  // per-wave [q][k]

    const unsigned short* Qp = Qb + (size_t)b * NVOX * 64;
    const unsigned short* Kp = Kb + (size_t)b * NVOX * 64;
    const unsigned short* Vp = Vb + (size_t)b * 64 * NVOX;

    // Q fragments (held for whole kernel): row q = lane&15, c-slices of 8
    int l15 = lane & 15;
    int g4  = lane >> 4;            // 0..3
    int csl = g4 * 8;
    int qrow = q0 + w * 16 + l15;
    s16x8 qf0 = *(const s16x8*)&Qp[(size_t)qrow * 64 + csl];
    s16x8 qf1 = *(const s16x8*)&Qp[(size_t)qrow * 64 + csl + 32];

    f32x4 acc_o[4] = {};            // [c-tile][reg], rows q = g4*4+reg
    float m_r[4], l_r[4];
    #pragma unroll
    for (int i = 0; i < 4; ++i) { m_r[i] = -1e30f; l_r[i] = 0.f; }

    // staging: thread t covers row sr, 32B chunk sc
    int sr = t >> 2;                // 0..63
    int sc = (t & 3) * 16;          // bf16 col offset

    s16x8 kr0, kr1, vr0, vr1;
    {   // prologue loads (first kv block of this split)
        const s16x8* pk = (const s16x8*)&Kp[((size_t)(kbase + sr)) * 64 + sc];
        kr0 = pk[0]; kr1 = pk[1];
        const s16x8* pv = (const s16x8*)&Vp[(size_t)sr * NVOX + kbase + sc];
        vr0 = pv[0]; vr1 = pv[1];
    }

    for (int it = 0; it < KVS / 64; ++it) {
        // write staged tile to LDS
        *(s16x8*)&Ks[sr][sc]     = kr0;
        *(s16x8*)&Ks[sr][sc + 8] = kr1;
        *(s16x8*)&Vs[sr][sc]     = vr0;
        *(s16x8*)&Vs[sr][sc + 8] = vr1;
        __syncthreads();

        // issue next tile's global loads (latency hides under compute)
        if (it < KVS / 64 - 1) {
            int k0n = kbase + (it + 1) * 64;
            const s16x8* pk = (const s16x8*)&Kp[((size_t)(k0n + sr)) * 64 + sc];
            kr0 = pk[0]; kr1 = pk[1];
            const s16x8* pv = (const s16x8*)&Vp[(size_t)sr * NVOX + k0n + sc];
            vr0 = pv[0]; vr1 = pv[1];
        }

        // ---- S = Q K^T  (4 k-tiles of 16) ----
        f32x4 sacc[4];
        #pragma unroll
        for (int kt = 0; kt < 4; ++kt) {
            s16x8 kf0 = *(const s16x8*)&Ks[kt * 16 + l15][csl];
            s16x8 kf1 = *(const s16x8*)&Ks[kt * 16 + l15][csl + 32];
            f32x4 z = {0.f, 0.f, 0.f, 0.f};
            sacc[kt] = __builtin_amdgcn_mfma_f32_16x16x32_bf16(qf0, kf0, z, 0, 0, 0);
            sacc[kt] = __builtin_amdgcn_mfma_f32_16x16x32_bf16(qf1, kf1, sacc[kt], 0, 0, 0);
        }

        // ---- online softmax (rows q = g4*4 + reg) ----
        float al[4];
        #pragma unroll
        for (int reg = 0; reg < 4; ++reg) {
            float rmax = fmaxf(fmaxf(sacc[0][reg], sacc[1][reg]),
                               fmaxf(sacc[2][reg], sacc[3][reg]));
            rmax = fmaxf(rmax, __shfl_xor(rmax, 1));
            rmax = fmaxf(rmax, __shfl_xor(rmax, 2));
            rmax = fmaxf(rmax, __shfl_xor(rmax, 4));
            rmax = fmaxf(rmax, __shfl_xor(rmax, 8));
            float mn = fmaxf(m_r[reg], rmax);
            al[reg] = __expf(m_r[reg] - mn);
            m_r[reg] = mn;
        }
        float p[4][4];   // [kt][reg]
        #pragma unroll
        for (int kt = 0; kt < 4; ++kt)
            #pragma unroll
            for (int reg = 0; reg < 4; ++reg)
                p[kt][reg] = __expf(sacc[kt][reg] - m_r[reg]);
        #pragma unroll
        for (int reg = 0; reg < 4; ++reg) {
            float rs = p[0][reg] + p[1][reg] + p[2][reg] + p[3][reg];
            rs += __shfl_xor(rs, 1);
            rs += __shfl_xor(rs, 2);
            rs += __shfl_xor(rs, 4);
            rs += __shfl_xor(rs, 8);
            l_r[reg] = l_r[reg] * al[reg] + rs;
        }
        // write P (bf16) to per-wave LDS: row g4*4+reg, col kt*16+l15
        #pragma unroll
        for (int kt = 0; kt < 4; ++kt)
            #pragma unroll
            for (int reg = 0; reg < 4; ++reg)
                Ps[w][g4 * 4 + reg][kt * 16 + l15] = f2bf(p[kt][reg]);
        // rescale O accumulator
        #pragma unroll
        for (int ct = 0; ct < 4; ++ct)
            #pragma unroll
            for (int reg = 0; reg < 4; ++reg)
                acc_o[ct][reg] *= al[reg];

        // ---- PV: A = P frag (row q = l15, k-slice), B = V^T frag ----
        s16x8 pf0 = *(const s16x8*)&Ps[w][l15][csl];
        s16x8 pf1 = *(const s16x8*)&Ps[w][l15][csl + 32];
        #pragma unroll
        for (int ct = 0; ct < 4; ++ct) {
            s16x8 vf0 = *(const s16x8*)&Vs[ct * 16 + l15][csl];
            s16x8 vf1 = *(const s16x8*)&Vs[ct * 16 + l15][csl + 32];
            acc_o[ct] = __builtin_amdgcn_mfma_f32_16x16x32_bf16(pf0, vf0, acc_o[ct], 0, 0, 0);
            acc_o[ct] = __builtin_amdgcn_mfma_f32_16x16x32_bf16(pf1, vf1, acc_o[ct], 0, 0, 0);
        }
        __syncthreads();   // all LDS reads done before next overwrite
    }

    // epilogue: write UNNORMALIZED partial O + per-row m,l
    #pragma unroll
    for (int ct = 0; ct < 4; ++ct)
        #pragma unroll
        for (int reg = 0; reg < 4; ++reg) {
            int q = q0 + w * 16 + g4 * 4 + reg;
            Opart[(((size_t)split * BATCH + b) * NVOX + q) * 64 + ct * 16 + l15] =
                acc_o[ct][reg];
        }
    if (l15 == 0) {
        #pragma unroll
        for (int reg = 0; reg < 4; ++reg) {
            int q = q0 + w * 16 + g4 * 4 + reg;
            Mpart[((size_t)split * BATCH + b) * NVOX + q] = m_r[reg];
            Lpart[((size_t)split * BATCH + b) * NVOX + q] = l_r[reg];
        }
    }
}

// ---------------------------------------------------------------------------
// Kernel 4: split-combine + output projection (64x64) + bias + residual.
// ---------------------------------------------------------------------------
__global__ __launch_bounds__(256) void k_outproj(const float* __restrict__ Opart,
                                                 const float* __restrict__ Mpart,
                                                 const float* __restrict__ Lpart,
                                                 const float* __restrict__ Wout,
                                                 const float* __restrict__ obias,
                                                 const float* __restrict__ x,
                                                 float* __restrict__ out) {
    int b  = blockIdx.x >> 6;
    int n0 = (blockIdx.x & 63) * 64;
    int t  = threadIdx.x;
    __shared__ float os[64][65];       // [n][c] +1 pad
    __shared__ float scs[64][4];       // per-row combine scales

    if (t < 64) {
        size_t qg = (size_t)b * NVOX + n0 + t;
        float m[SPLITS], l[SPLITS];
        #pragma unroll
        for (int s = 0; s < SPLITS; ++s) {
            m[s] = Mpart[(size_t)s * BATCH * NVOX + qg];
            l[s] = Lpart[(size_t)s * BATCH * NVOX + qg];
        }
        float mm = fmaxf(fmaxf(m[0], m[1]), fmaxf(m[2], m[3]));
        float e[SPLITS], lsum = 0.f;
        #pragma unroll
        for (int s = 0; s < SPLITS; ++s) { e[s] = __expf(m[s] - mm); lsum += l[s] * e[s]; }
        float inv = 1.f / lsum;
        #pragma unroll
        for (int s = 0; s < SPLITS; ++s) scs[t][s] = e[s] * inv;
    }
    __syncthreads();

    for (int i = t; i < 64 * 16; i += 256) {
        int n  = i >> 4;
        int c4 = (i & 15) * 4;
        size_t base = ((size_t)(b * NVOX + n0 + n)) * 64 + c4;
        float4 a = {0.f, 0.f, 0.f, 0.f};
        #pragma unroll
        for (int s = 0; s < SPLITS; ++s) {
            float4 v = *(const float4*)&Opart[(size_t)s * BATCH * NVOX * 64 + base];
            float f = scs[n][s];
            a.x += f * v.x; a.y += f * v.y; a.z += f * v.z; a.w += f * v.w;
        }
        os[n][c4 + 0] = a.x; os[n][c4 + 1] = a.y;
        os[n][c4 + 2] = a.z; os[n][c4 + 3] = a.w;
    }
    __syncthreads();

    int nl = t & 63;
    int dg = t >> 6;
    float r[64];
    #pragma unroll
    for (int c = 0; c < 64; ++c) r[c] = os[nl][c];
    #pragma unroll 4
    for (int j = 0; j < 16; ++j) {
        int d = dg * 16 + j;
        const float* wv = &Wout[d * 64];
        float acc = obias[d];
        #pragma unroll
        for (int c = 0; c < 64; ++c) acc += wv[c] * r[c];
        size_t idx = ((size_t)(b * CH + d)) * NVOX + n0 + nl;
        out[idx] = acc + x[idx];
    }
}

// ---------------------------------------------------------------------------
extern "C" void kernel_launch(void* const* d_in, const int* in_sizes, int n_in,
                              void* d_out, int out_size, void* d_ws, size_t ws_size,
                              hipStream_t stream) {
    const float* x     = (const float*)d_in[0];
    const float* gw    = (const float*)d_in[1];
    const float* gb    = (const float*)d_in[2];
    const float* Wqkv  = (const float*)d_in[3];
    const float* Wout  = (const float*)d_in[4];
    const float* obias = (const float*)d_in[5];
    float* out = (float*)d_out;

    float* ws    = (float*)d_ws;
    float* stats = ws;                                     // 256 floats
    unsigned short* Qb = (unsigned short*)(ws + 256);      // 2 MB each
    unsigned short* Kb = Qb + (size_t)BATCH * NVOX * 64;
    unsigned short* Vb = Kb + (size_t)BATCH * NVOX * 64;
    float* Opart = (float*)(Vb + (size_t)BATCH * NVOX * 64);      // 16 MB
    float* Mpart = Opart + (size_t)SPLITS * BATCH * NVOX * 64;    // 256 KB
    float* Lpart = Mpart + (size_t)SPLITS * BATCH * NVOX;         // 256 KB

    k_gnstats<<<BATCH * NGRP,        256, 0, stream>>>(x, stats);
    k_qkv   <<<BATCH * 64,           256, 0, stream>>>(x, stats, gw, gb, Wqkv, Qb, Kb, Vb);
    k_attn  <<<BATCH * 64 * SPLITS,  256, 0, stream>>>(Qb, Kb, Vb, Opart, Mpart, Lpart);
    k_outproj<<<BATCH * 64,          256, 0, stream>>>(Opart, Mpart, Lpart, Wout, obias, x, out);
}